// Round 10
// baseline (209.244 us; speedup 1.0000x reference)
//
#include <hip/hip_runtime.h>
#include <cstddef>

// DCT-II matrix (float32 cast of numpy's float64 values)
static constexpr float D8[8][8] = {
  { 0.35355339059327373f, 0.35355339059327373f, 0.35355339059327373f, 0.35355339059327373f,
    0.35355339059327373f, 0.35355339059327373f, 0.35355339059327373f, 0.35355339059327373f},
  { 0.4903926402016152f,  0.4157348061512726f,  0.27778511650980114f, 0.09754516100806417f,
   -0.09754516100806417f,-0.27778511650980114f,-0.4157348061512726f, -0.4903926402016152f},
  { 0.46193976625564337f, 0.19134171618254492f,-0.19134171618254492f,-0.46193976625564337f,
   -0.46193976625564337f,-0.19134171618254492f, 0.19134171618254492f, 0.46193976625564337f},
  { 0.4157348061512726f, -0.09754516100806417f,-0.4903926402016152f, -0.27778511650980114f,
    0.27778511650980114f, 0.4903926402016152f,  0.09754516100806417f,-0.4157348061512726f},
  { 0.35355339059327373f,-0.35355339059327373f,-0.35355339059327373f, 0.35355339059327373f,
    0.35355339059327373f,-0.35355339059327373f,-0.35355339059327373f, 0.35355339059327373f},
  { 0.27778511650980114f,-0.4903926402016152f,  0.09754516100806417f, 0.4157348061512726f,
   -0.4157348061512726f, -0.09754516100806417f, 0.4903926402016152f, -0.27778511650980114f},
  { 0.19134171618254492f,-0.46193976625564337f, 0.46193976625564337f,-0.19134171618254492f,
   -0.19134171618254492f, 0.46193976625564337f,-0.46193976625564337f, 0.19134171618254492f},
  { 0.09754516100806417f,-0.27778511650980114f, 0.4157348061512726f, -0.4903926402016152f,
    0.4903926402016152f, -0.4157348061512726f,  0.27778511650980114f,-0.09754516100806417f},
};

// Quality-95 quant tables: q = clamp(floor((base*10+50)/100), 1, 255)
static constexpr float QLt[8][8] = {
  {2,1,1,2,2,4,5,6},
  {1,1,1,2,3,6,6,6},
  {1,1,2,2,4,6,7,6},
  {1,2,2,3,5,9,8,6},
  {2,2,4,6,7,11,10,8},
  {2,4,6,6,8,10,11,9},
  {5,6,8,9,10,12,12,10},
  {7,9,10,10,11,10,10,10},
};
static constexpr float QCt[8][8] = {
  {2,2,2,5,10,10,10,10},
  {2,2,3,7,10,10,10,10},
  {2,3,6,10,10,10,10,10},
  {5,7,10,10,10,10,10,10},
  {10,10,10,10,10,10,10,10},
  {10,10,10,10,10,10,10,10},
  {10,10,10,10,10,10,10,10},
  {10,10,10,10,10,10,10,10},
};

static constexpr float C255  = (float)(1.0/255.0);  // fl(1/255): matches jnp's f32 divisor
static constexpr float RC255 = 1.0f / C255;         // correctly-rounded reciprocal (constexpr IEEE)

// Markstein exactly-rounded division by constant c with precomputed r = fl(1/c):
// bit-identical to IEEE x/c, 3 VALU ops.
__device__ __forceinline__ float exact_div(float x, float c, float r) {
  float q0 = x * r;
  float e  = fmaf(-c, q0, x);
  return fmaf(e, r, q0);
}

// u[k] = sum_j D8[k][j] * x[j]
__device__ __forceinline__ void dct8(const float x[8], float u[8]) {
  #pragma unroll
  for (int k = 0; k < 8; ++k) {
    float a = D8[k][0] * x[0];
    #pragma unroll
    for (int j = 1; j < 8; ++j) a += D8[k][j] * x[j];
    u[k] = a;
  }
}

// u[j] = sum_m x[m] * D8[m][j]
__device__ __forceinline__ void idct8(const float x[8], float u[8]) {
  #pragma unroll
  for (int j = 0; j < 8; ++j) {
    float a = x[0] * D8[0][j];
    #pragma unroll
    for (int m = 1; m < 8; ++m) a += x[m] * D8[m][j];
    u[j] = a;
  }
}

// 8x8 transpose via group-local LDS scratch, bank-engineered (R9-verified:
// conflicts 1.97M -> 393K): row stride 13 (odd), group stride 104 (104%32=8).
// write: bank=(8g+13m+l)%32 fixed m -> 2-way (free); read: bank=(8g+13l+m)%32
// fixed m -> 2-way (free). Scalar DS ops, same-wave lockstep, no barrier.
__device__ __forceinline__ void xpose_scr(float v[8], int l, float* S) {
  #pragma unroll
  for (int m = 0; m < 8; ++m) S[m*13 + l] = v[m];   // write my column
  asm volatile("" ::: "memory");                    // pin write<read order
  float u[8];
  #pragma unroll
  for (int m = 0; m < 8; ++m) u[m] = S[l*13 + m];   // read my row
  asm volatile("" ::: "memory");
  #pragma unroll
  for (int m = 0; m < 8; ++m) v[m] = u[m];
}

__device__ __forceinline__ void quant8(float v[8], const float* QT, const float* RQ) {
  float4 Q0 = *(const float4*)&QT[0];
  float4 Q1 = *(const float4*)&QT[4];
  float4 R0 = *(const float4*)&RQ[0];
  float4 R1 = *(const float4*)&RQ[4];
  float qv[8] = {Q0.x,Q0.y,Q0.z,Q0.w,Q1.x,Q1.y,Q1.z,Q1.w};
  float rv[8] = {R0.x,R0.y,R0.z,R0.w,R1.x,R1.y,R1.z,R1.w};
  #pragma unroll
  for (int m = 0; m < 8; ++m)
    v[m] = rintf(exact_div(v[m], qv[m], rv[m])) * qv[m];
}

// Full per-block pipeline; v holds spatial row `l` in/out.
__device__ __forceinline__ void jblk8(float v[8], int l, float* S,
                                      const float* QT, const float* RQ) {
  float u[8];
  dct8(v, u);
  xpose_scr(u, l, S);
  dct8(u, v);
  quant8(v, QT, RQ);
  idct8(v, u);
  xpose_scr(u, l, S);
  idct8(u, v);
}

// =====================================================================
// K1: chroma pipeline. One 8-lane group = one 16x16 input region = one Cb
// block + one Cr block. Lane l owns input rows 2l, 2l+1 of the region ->
// chroma row l entirely in-lane (no shuffles). Rec'd (centered) chroma
// planes written to workspace [img][plane][256][256].
// Grid (32 region-rows, 32 images), 256 threads = 32 region-cols.
// =====================================================================
__global__ __launch_bounds__(256) void chroma_k(const float* __restrict__ in,
                                                float* __restrict__ ws)
{
  __shared__ __align__(16) float Scr[32][104];
  __shared__ __align__(16) float QTc[8][8];   // [col l][row m] = QC[m][l]
  __shared__ __align__(16) float RQc[8][8];

  const int t   = threadIdx.x;
  const int g   = t >> 3;       // region col 0..31
  const int l   = t & 7;        // chroma row within block
  const int ry  = blockIdx.x;   // region row 0..31
  const int img = blockIdx.y;   // 0..31

  if (t < 64) {
    const int i = t >> 3, m = t & 7;
    const float q = QCt[m][i];
    QTc[i][m] = q;
    RQc[i][m] = 1.0f / q;
  }

  // Convert 2 rows x 16 px, downsample 2x2 in-lane. Reference order kept:
  // ((c00+c01)+(c10+c11))*0.25 - 128.
  float scb[8], scr[8];
  #pragma unroll
  for (int rr = 0; rr < 2; ++rr) {
    const int row = ry*16 + 2*l + rr;
    const float* bp = in + ((size_t)img*512 + row)*1536 + (size_t)g*48;
    #pragma unroll
    for (int cq = 0; cq < 4; ++cq) {
      float4 A = ((const float4*)bp)[cq*3+0];
      float4 B = ((const float4*)bp)[cq*3+1];
      float4 C = ((const float4*)bp)[cq*3+2];
      float px[12] = {A.x,A.y,A.z,A.w,B.x,B.y,B.z,B.w,C.x,C.y,C.z,C.w};
      float cbv[4], crv[4];
      #pragma unroll
      for (int p = 0; p < 4; ++p) {
        float r = floorf(exact_div(px[3*p+0], C255, RC255));
        float gg = floorf(exact_div(px[3*p+1], C255, RC255));
        float b = floorf(exact_div(px[3*p+2], C255, RC255));
        cbv[p] = -0.168736f*r - 0.331264f*gg + 0.5f*b + 128.0f;
        crv[p] =  0.5f*r - 0.418688f*gg - 0.081312f*b + 128.0f;
      }
      const float hb0 = cbv[0]+cbv[1], hb1 = cbv[2]+cbv[3];
      const float hr0 = crv[0]+crv[1], hr1 = crv[2]+crv[3];
      if (rr == 0) { scb[2*cq] = hb0; scb[2*cq+1] = hb1;
                     scr[2*cq] = hr0; scr[2*cq+1] = hr1; }
      else         { scb[2*cq] += hb0; scb[2*cq+1] += hb1;
                     scr[2*cq] += hr0; scr[2*cq+1] += hr1; }
    }
  }
  float vcb[8], vcr[8];
  #pragma unroll
  for (int k = 0; k < 8; ++k) {
    vcb[k] = scb[k]*0.25f - 128.0f;
    vcr[k] = scr[k]*0.25f - 128.0f;
  }
  __syncthreads();   // tables visible (Scr is group-private, same-wave)

  jblk8(vcb, l, &Scr[g][0], &QTc[l][0], &RQc[l][0]);
  jblk8(vcr, l, &Scr[g][0], &QTc[l][0], &RQc[l][0]);

  float* wp = ws + (size_t)img*131072 + (size_t)(ry*8 + l)*256 + g*8;
  *(float4*)&wp[0]       = make_float4(vcb[0],vcb[1],vcb[2],vcb[3]);
  *(float4*)&wp[4]       = make_float4(vcb[4],vcb[5],vcb[6],vcb[7]);
  *(float4*)&wp[65536]   = make_float4(vcr[0],vcr[1],vcr[2],vcr[3]);
  *(float4*)&wp[65540]   = make_float4(vcr[4],vcr[5],vcr[6],vcr[7]);
}

// =====================================================================
// K2: luma pipeline + output. One thread = one luma block row. NO inter-
// phase barriers (only the initial table barrier): each thread loads its 8
// px, converts Y, runs the register/group-scratch DCT pipeline, reads the
// rec'd chroma from ws (L2-resident), and writes its output row. Waves run
// fully decoupled -> TLP hides load latency. Grid (4, 32, 32), 256 thr.
// =====================================================================
__global__ __launch_bounds__(256) void recon_k(const float* __restrict__ in,
                                               const float* __restrict__ ws,
                                               float* __restrict__ out)
{
  __shared__ __align__(16) float Scr[32][104];
  __shared__ __align__(16) float QTl[8][8];   // [col l][row m] = QL[m][l]
  __shared__ __align__(16) float RQl[8][8];

  const int t   = threadIdx.x;
  const int g   = t >> 3;       // group 0..31
  const int l   = t & 7;
  const int br  = g >> 4;       // luma block-row (0..1)
  const int bc  = g & 15;       // luma block-col (0..15)
  const int tx  = blockIdx.x;   // 0..3
  const int ty  = blockIdx.y;   // 0..31
  const int img = blockIdx.z;   // 0..31

  if (t < 64) {
    const int i = t >> 3, m = t & 7;
    const float q = QLt[m][i];
    QTl[i][m] = q;
    RQl[i][m] = 1.0f / q;
  }

  const int row  = ty*16 + br*8 + l;
  const int col0 = tx*128 + bc*8;
  const float* rp = in + ((size_t)img*512 + row)*1536 + (size_t)col0*3;
  float4 P0 = ((const float4*)rp)[0];
  float4 P1 = ((const float4*)rp)[1];
  float4 P2 = ((const float4*)rp)[2];
  float4 P3 = ((const float4*)rp)[3];
  float4 P4 = ((const float4*)rp)[4];
  float4 P5 = ((const float4*)rp)[5];
  float px[24] = {P0.x,P0.y,P0.z,P0.w,P1.x,P1.y,P1.z,P1.w,
                  P2.x,P2.y,P2.z,P2.w,P3.x,P3.y,P3.z,P3.w,
                  P4.x,P4.y,P4.z,P4.w,P5.x,P5.y,P5.z,P5.w};
  float vY[8];
  #pragma unroll
  for (int p = 0; p < 8; ++p) {
    float r = floorf(exact_div(px[3*p+0], C255, RC255));
    float gg = floorf(exact_div(px[3*p+1], C255, RC255));
    float b = floorf(exact_div(px[3*p+2], C255, RC255));
    vY[p] = (0.299f*r + 0.587f*gg + 0.114f*b) - 128.0f;
  }
  __syncthreads();   // table visibility (the only WG barrier)

  jblk8(vY, l, &Scr[g][0], &QTl[l][0], &RQl[l][0]);

  // rec'd chroma for this row: 4 Cb + 4 Cr (centered), float4-aligned.
  const int crow = row >> 1;
  const int ccol = tx*64 + bc*4;
  const float* cp = ws + (size_t)img*131072 + (size_t)crow*256 + ccol;
  float4 Cb4 = *(const float4*)cp;
  float4 Cr4 = *(const float4*)(cp + 65536);
  float cbq[4] = {Cb4.x, Cb4.y, Cb4.z, Cb4.w};
  float crq[4] = {Cr4.x, Cr4.y, Cr4.z, Cr4.w};

  float ov[24];
  #pragma unroll
  for (int p = 0; p < 8; ++p) {
    float y2  = vY[p] + 128.0f;
    float cb2 = cbq[p>>1] + 128.0f;
    float cr2 = crq[p>>1] + 128.0f;
    float r2 = y2 + 1.402f*(cr2 - 128.0f);
    float g2 = y2 - 0.344136f*(cb2 - 128.0f) - 0.714136f*(cr2 - 128.0f);
    float b2 = y2 + 1.772f*(cb2 - 128.0f);
    ov[3*p+0] = rintf(fminf(fmaxf(r2, 0.0f), 255.0f)) * C255;
    ov[3*p+1] = rintf(fminf(fmaxf(g2, 0.0f), 255.0f)) * C255;
    ov[3*p+2] = rintf(fminf(fmaxf(b2, 0.0f), 255.0f)) * C255;
  }
  float* op = out + ((size_t)img*512 + row)*1536 + (size_t)col0*3;
  ((float4*)op)[0] = make_float4(ov[0], ov[1], ov[2], ov[3]);
  ((float4*)op)[1] = make_float4(ov[4], ov[5], ov[6], ov[7]);
  ((float4*)op)[2] = make_float4(ov[8], ov[9], ov[10],ov[11]);
  ((float4*)op)[3] = make_float4(ov[12],ov[13],ov[14],ov[15]);
  ((float4*)op)[4] = make_float4(ov[16],ov[17],ov[18],ov[19]);
  ((float4*)op)[5] = make_float4(ov[20],ov[21],ov[22],ov[23]);
}

// =====================================================================
// Fallback: round-9 verified single kernel (used if ws_size < 16.8 MB).
// =====================================================================
__global__ __launch_bounds__(256) void jpeg_rt_fb(const float* __restrict__ in,
                                                  float* __restrict__ out)
{
  __shared__ __align__(16) float Yp[16][132];
  __shared__ __align__(16) float Scr[32][104];
  __shared__ __align__(16) float Cbp[8][68];
  __shared__ __align__(16) float Crp[8][68];
  __shared__ __align__(16) float QTs[2][8][8];
  __shared__ __align__(16) float RQs[2][8][8];

  const int t   = threadIdx.x;
  const int tx  = blockIdx.x;
  const int ty  = blockIdx.y;
  const int img = blockIdx.z;
  const int pr = t >> 5;
  const int pc = t & 31;

  if (t < 128) {
    const int pl = t >> 6, i = (t >> 3) & 7, m = t & 7;
    const float q = pl ? QCt[m][i] : QLt[m][i];
    QTs[pl][i][m] = q;
    RQs[pl][i][m] = 1.0f / q;
  }

  {
    float yv[2][4], cbv[2][4], crv[2][4];
    #pragma unroll
    for (int rr = 0; rr < 2; ++rr) {
      const size_t grow = (size_t)img * 512 + (size_t)(ty*16 + 2*pr + rr);
      const float* rp = in + (grow*512 + (size_t)(tx*128 + 4*pc))*3;
      float4 A = ((const float4*)rp)[0];
      float4 Bq = ((const float4*)rp)[1];
      float4 Cq = ((const float4*)rp)[2];
      float px[12] = {A.x,A.y,A.z,A.w,Bq.x,Bq.y,Bq.z,Bq.w,Cq.x,Cq.y,Cq.z,Cq.w};
      #pragma unroll
      for (int p = 0; p < 4; ++p) {
        float r = floorf(exact_div(px[3*p+0], C255, RC255));
        float g = floorf(exact_div(px[3*p+1], C255, RC255));
        float b = floorf(exact_div(px[3*p+2], C255, RC255));
        float y  =  0.299f*r + 0.587f*g + 0.114f*b;
        float cb = -0.168736f*r - 0.331264f*g + 0.5f*b + 128.0f;
        float cr =  0.5f*r - 0.418688f*g - 0.081312f*b + 128.0f;
        yv[rr][p]  = y - 128.0f;
        cbv[rr][p] = cb;
        crv[rr][p] = cr;
      }
    }
    *(float4*)&Yp[2*pr+0][4*pc] = make_float4(yv[0][0],yv[0][1],yv[0][2],yv[0][3]);
    *(float4*)&Yp[2*pr+1][4*pc] = make_float4(yv[1][0],yv[1][1],yv[1][2],yv[1][3]);
    float cb0 = ((cbv[0][0]+cbv[0][1]) + (cbv[1][0]+cbv[1][1]))*0.25f - 128.0f;
    float cb1 = ((cbv[0][2]+cbv[0][3]) + (cbv[1][2]+cbv[1][3]))*0.25f - 128.0f;
    float cr0 = ((crv[0][0]+crv[0][1]) + (crv[1][0]+crv[1][1]))*0.25f - 128.0f;
    float cr1 = ((crv[0][2]+crv[0][3]) + (crv[1][2]+crv[1][3]))*0.25f - 128.0f;
    *(float2*)&Cbp[pr][2*pc] = make_float2(cb0, cb1);
    *(float2*)&Crp[pr][2*pc] = make_float2(cr0, cr1);
  }
  __syncthreads();

  {
    const int b = t >> 3, l = t & 7;
    const int br = b >> 4, bc = b & 15;
    float* rowp = &Yp[br*8 + l][bc*8];
    float4 L0 = *(const float4*)&rowp[0];
    float4 L1 = *(const float4*)&rowp[4];
    float v[8] = {L0.x, L0.y, L0.z, L0.w, L1.x, L1.y, L1.z, L1.w};
    jblk8(v, l, &Scr[b][0], &QTs[0][l][0], &RQs[0][l][0]);
    *(float4*)&rowp[0] = make_float4(v[0],v[1],v[2],v[3]);
    *(float4*)&rowp[4] = make_float4(v[4],v[5],v[6],v[7]);
  }
  if (t < 128) {
    const int g = t >> 3, l = t & 7;
    float* plane = (g & 8) ? &Crp[0][0] : &Cbp[0][0];
    float* rowp = plane + l*68 + (g & 7)*8;
    float4 L0 = *(const float4*)&rowp[0];
    float4 L1 = *(const float4*)&rowp[4];
    float v[8] = {L0.x, L0.y, L0.z, L0.w, L1.x, L1.y, L1.z, L1.w};
    jblk8(v, l, &Scr[g][0], &QTs[1][l][0], &RQs[1][l][0]);
    *(float4*)&rowp[0] = make_float4(v[0],v[1],v[2],v[3]);
    *(float4*)&rowp[4] = make_float4(v[4],v[5],v[6],v[7]);
  }
  __syncthreads();

  {
    float4 Y0 = *(const float4*)&Yp[2*pr+0][4*pc];
    float4 Y1 = *(const float4*)&Yp[2*pr+1][4*pc];
    float y0[4] = {Y0.x, Y0.y, Y0.z, Y0.w};
    float y1[4] = {Y1.x, Y1.y, Y1.z, Y1.w};
    float2 cbp2 = *(const float2*)&Cbp[pr][2*pc];
    float2 crp2 = *(const float2*)&Crp[pr][2*pc];
    float cbq[2] = {cbp2.x, cbp2.y};
    float crq[2] = {crp2.x, crp2.y};
    #pragma unroll
    for (int rr = 0; rr < 2; ++rr) {
      float ov[12];
      #pragma unroll
      for (int p = 0; p < 4; ++p) {
        float y2  = (rr ? y1[p] : y0[p]) + 128.0f;
        float cb2 = cbq[p>>1] + 128.0f;
        float cr2 = crq[p>>1] + 128.0f;
        float r2 = y2 + 1.402f*(cr2 - 128.0f);
        float g2 = y2 - 0.344136f*(cb2 - 128.0f) - 0.714136f*(cr2 - 128.0f);
        float b2 = y2 + 1.772f*(cb2 - 128.0f);
        ov[3*p+0] = rintf(fminf(fmaxf(r2, 0.0f), 255.0f)) * C255;
        ov[3*p+1] = rintf(fminf(fmaxf(g2, 0.0f), 255.0f)) * C255;
        ov[3*p+2] = rintf(fminf(fmaxf(b2, 0.0f), 255.0f)) * C255;
      }
      const size_t grow = (size_t)img * 512 + (size_t)(ty*16 + 2*pr + rr);
      float* op = out + (grow*512 + (size_t)(tx*128 + 4*pc))*3;
      ((float4*)op)[0] = make_float4(ov[0],ov[1],ov[2],ov[3]);
      ((float4*)op)[1] = make_float4(ov[4],ov[5],ov[6],ov[7]);
      ((float4*)op)[2] = make_float4(ov[8],ov[9],ov[10],ov[11]);
    }
  }
}

extern "C" void kernel_launch(void* const* d_in, const int* in_sizes, int n_in,
                              void* d_out, int out_size, void* d_ws, size_t ws_size,
                              hipStream_t stream) {
  (void)in_sizes; (void)n_in; (void)out_size;
  const float* x = (const float*)d_in[0];
  float* out = (float*)d_out;
  const size_t WS_NEED = (size_t)32 * 2 * 256 * 256 * 4;  // 16.78 MB
  if (d_ws != nullptr && ws_size >= WS_NEED) {
    float* ws = (float*)d_ws;
    chroma_k<<<dim3(32, 32, 1), dim3(256), 0, stream>>>(x, ws);
    recon_k<<<dim3(4, 32, 32), dim3(256), 0, stream>>>(x, ws, out);
  } else {
    jpeg_rt_fb<<<dim3(4, 32, 32), dim3(256), 0, stream>>>(x, out);
  }
}

// Round 11
// 184.571 us; speedup vs baseline: 1.1337x; 1.1337x over previous
//
#include <hip/hip_runtime.h>
#include <cstddef>

// DCT-II matrix (float32 cast of numpy's float64 values)
static constexpr float D8[8][8] = {
  { 0.35355339059327373f, 0.35355339059327373f, 0.35355339059327373f, 0.35355339059327373f,
    0.35355339059327373f, 0.35355339059327373f, 0.35355339059327373f, 0.35355339059327373f},
  { 0.4903926402016152f,  0.4157348061512726f,  0.27778511650980114f, 0.09754516100806417f,
   -0.09754516100806417f,-0.27778511650980114f,-0.4157348061512726f, -0.4903926402016152f},
  { 0.46193976625564337f, 0.19134171618254492f,-0.19134171618254492f,-0.46193976625564337f,
   -0.46193976625564337f,-0.19134171618254492f, 0.19134171618254492f, 0.46193976625564337f},
  { 0.4157348061512726f, -0.09754516100806417f,-0.4903926402016152f, -0.27778511650980114f,
    0.27778511650980114f, 0.4903926402016152f,  0.09754516100806417f,-0.4157348061512726f},
  { 0.35355339059327373f,-0.35355339059327373f,-0.35355339059327373f, 0.35355339059327373f,
    0.35355339059327373f,-0.35355339059327373f,-0.35355339059327373f, 0.35355339059327373f},
  { 0.27778511650980114f,-0.4903926402016152f,  0.09754516100806417f, 0.4157348061512726f,
   -0.4157348061512726f, -0.09754516100806417f, 0.4903926402016152f, -0.27778511650980114f},
  { 0.19134171618254492f,-0.46193976625564337f, 0.46193976625564337f,-0.19134171618254492f,
   -0.19134171618254492f, 0.46193976625564337f,-0.46193976625564337f, 0.19134171618254492f},
  { 0.09754516100806417f,-0.27778511650980114f, 0.4157348061512726f, -0.4903926402016152f,
    0.4903926402016152f, -0.4157348061512726f,  0.27778511650980114f,-0.09754516100806417f},
};

// Quality-95 quant tables: q = clamp(floor((base*10+50)/100), 1, 255)
static constexpr float QLt[8][8] = {
  {2,1,1,2,2,4,5,6},
  {1,1,1,2,3,6,6,6},
  {1,1,2,2,4,6,7,6},
  {1,2,2,3,5,9,8,6},
  {2,2,4,6,7,11,10,8},
  {2,4,6,6,8,10,11,9},
  {5,6,8,9,10,12,12,10},
  {7,9,10,10,11,10,10,10},
};
static constexpr float QCt[8][8] = {
  {2,2,2,5,10,10,10,10},
  {2,2,3,7,10,10,10,10},
  {2,3,6,10,10,10,10,10},
  {5,7,10,10,10,10,10,10},
  {10,10,10,10,10,10,10,10},
  {10,10,10,10,10,10,10,10},
  {10,10,10,10,10,10,10,10},
  {10,10,10,10,10,10,10,10},
};

static constexpr float C255  = (float)(1.0/255.0);  // fl(1/255): matches jnp's f32 divisor
static constexpr float RC255 = 1.0f / C255;         // correctly-rounded reciprocal (constexpr IEEE)

// Markstein exactly-rounded division by constant c with precomputed r = fl(1/c):
// bit-identical to IEEE x/c, 3 VALU ops. Used where a floor/rint decision
// depends on the quotient.
__device__ __forceinline__ float exact_div(float x, float c, float r) {
  float q0 = x * r;
  float e  = fmaf(-c, q0, x);
  return fmaf(e, r, q0);
}

// u[k] = sum_j D8[k][j] * x[j]
__device__ __forceinline__ void dct8(const float x[8], float u[8]) {
  #pragma unroll
  for (int k = 0; k < 8; ++k) {
    float a = D8[k][0] * x[0];
    #pragma unroll
    for (int j = 1; j < 8; ++j) a += D8[k][j] * x[j];
    u[k] = a;
  }
}

// u[j] = sum_m x[m] * D8[m][j]
__device__ __forceinline__ void idct8(const float x[8], float u[8]) {
  #pragma unroll
  for (int j = 0; j < 8; ++j) {
    float a = x[0] * D8[0][j];
    #pragma unroll
    for (int m = 1; m < 8; ++m) a += x[m] * D8[m][j];
    u[j] = a;
  }
}

// 8x8 transpose via group-local LDS scratch, bank-engineered (R9-verified:
// conflicts 1.97M -> 393K): row stride 13 (odd), group stride 104 (104%32=8).
// write m: bank=(8g+13m+l)%32, fixed m -> exactly 2-way (free, m136);
// read  m: bank=(8g+13l+m)%32, 13 invertible mod 32 -> exactly 2-way (free).
// All-scalar DS ops, zero VALU, same-wave lockstep (no barrier needed).
__device__ __forceinline__ void xpose_scr(float v[8], int l, float* S) {
  #pragma unroll
  for (int m = 0; m < 8; ++m) S[m*13 + l] = v[m];   // write my column
  asm volatile("" ::: "memory");                    // pin write<read order
  float u[8];
  #pragma unroll
  for (int m = 0; m < 8; ++m) u[m] = S[l*13 + m];   // read my row
  asm volatile("" ::: "memory");
  #pragma unroll
  for (int m = 0; m < 8; ++m) v[m] = u[m];
}

__device__ __forceinline__ void quant8(float v[8], const float* QT, const float* RQ) {
  float4 Q0 = *(const float4*)&QT[0];
  float4 Q1 = *(const float4*)&QT[4];
  float4 R0 = *(const float4*)&RQ[0];
  float4 R1 = *(const float4*)&RQ[4];
  float qv[8] = {Q0.x,Q0.y,Q0.z,Q0.w,Q1.x,Q1.y,Q1.z,Q1.w};
  float rv[8] = {R0.x,R0.y,R0.z,R0.w,R1.x,R1.y,R1.z,R1.w};
  #pragma unroll
  for (int m = 0; m < 8; ++m)
    v[m] = rintf(exact_div(v[m], qv[m], rv[m])) * qv[m];
}

// Full per-block pipeline; v holds spatial row `l` in/out.
__device__ __forceinline__ void jblk8(float v[8], int l, float* S,
                                      const float* QT, const float* RQ) {
  float u[8];
  dct8(v, u);
  xpose_scr(u, l, S);
  dct8(u, v);
  quant8(v, QT, RQ);
  idct8(v, u);
  xpose_scr(u, l, S);
  idct8(u, v);
}

struct Row24 { float4 a, b, c, d, e, f; };   // 24 contiguous floats (8 RGB px)

__device__ __forceinline__ Row24 loadrow(const float* __restrict__ p) {
  const float4* q = (const float4*)p;
  Row24 r;
  r.a = q[0]; r.b = q[1]; r.c = q[2]; r.d = q[3]; r.e = q[4]; r.f = q[5];
  return r;
}

// Color-convert one row of 8 pixels -> level-shifted luma yv[8] + the 2x2
// downsampled chroma (4 values; vertical pair via shfl_xor(1): lanes l, l^1
// hold adjacent image rows). Input clamp dropped (R8-proven): x in [0,1) =>
// floor(x/fl(1/255)) is already in [0,255].
__device__ __forceinline__ void convert_row(const Row24& R, float yv[8],
                                            float cbds[4], float crds[4]) {
  float px[24] = {R.a.x,R.a.y,R.a.z,R.a.w, R.b.x,R.b.y,R.b.z,R.b.w,
                  R.c.x,R.c.y,R.c.z,R.c.w, R.d.x,R.d.y,R.d.z,R.d.w,
                  R.e.x,R.e.y,R.e.z,R.e.w, R.f.x,R.f.y,R.f.z,R.f.w};
  float cbv[8], crv[8];
  #pragma unroll
  for (int p = 0; p < 8; ++p) {
    float rc = floorf(exact_div(px[3*p+0], C255, RC255));
    float gc = floorf(exact_div(px[3*p+1], C255, RC255));
    float bc = floorf(exact_div(px[3*p+2], C255, RC255));
    float y  =  0.299f*rc + 0.587f*gc + 0.114f*bc;
    float cb = -0.168736f*rc - 0.331264f*gc + 0.5f*bc + 128.0f;
    float cr =  0.5f*rc - 0.418688f*gc - 0.081312f*bc + 128.0f;
    yv[p]  = y - 128.0f;
    cbv[p] = cb;
    crv[p] = cr;
  }
  #pragma unroll
  for (int k = 0; k < 4; ++k) {
    float hcb = cbv[2*k] + cbv[2*k+1];      // reference order: (c00+c01)+(c10+c11)
    float hcr = crv[2*k] + crv[2*k+1];
    float ocb = __shfl_xor(hcb, 1, 64);
    float ocr = __shfl_xor(hcr, 1, 64);
    cbds[k] = (hcb + ocb)*0.25f - 128.0f;
    crds[k] = (hcr + ocr)*0.25f - 128.0f;
  }
}

// Tile: 16 rows x 128 cols. Grid (4, 32, 32) = 4096 WGs x 256 threads.
// R8's lean structure (luma never in LDS: row loaded per-lane in DCT layout,
// vY lives in 8 VGPRs across phases; LDS 18.7KB -> 8 WG/CU occupancy cap)
// + R9's bank-engineered scratch transpose (the cell of the R8/R9 cross
// product not yet measured).
__global__ __launch_bounds__(256) void jpeg_rt(const float* __restrict__ in,
                                               float* __restrict__ out)
{
  __shared__ __align__(16) float Scr[32][104];  // per-group transpose scratch
  __shared__ __align__(16) float Cbp[8][68];    // half-res chroma planes
  __shared__ __align__(16) float Crp[8][68];
  __shared__ __align__(16) float QTs[2][8][8];  // [plane][col l][row m] = Q[m][l]
  __shared__ __align__(16) float RQs[2][8][8];  // correctly-rounded 1/Q

  const int t   = threadIdx.x;  // 0..255
  const int g   = t >> 3;       // group 0..31
  const int l   = t & 7;        // row within 8x8 block
  const int br  = g >> 4;       // luma block-row (0..1)
  const int bc  = g & 15;       // luma block-col (0..15)
  const int tx  = blockIdx.x;   // 0..3
  const int ty  = blockIdx.y;   // 0..31
  const int img = blockIdx.z;   // 0..31

  // Quant tables (transposed) + exact reciprocals.
  if (t < 128) {
    const int pl = t >> 6, i = (t >> 3) & 7, m = t & 7;
    const float q = pl ? QCt[m][i] : QLt[m][i];
    QTs[pl][i][m] = q;
    RQs[pl][i][m] = 1.0f / q;
  }

  const size_t imgbase = (size_t)img * (512*512);
  const int row  = ty*16 + br*8 + l;   // this thread's image row
  const int col0 = tx*128 + bc*8;

  // ---------------- stage 1: load one 8-px row, convert, emit chroma to LDS
  float vY[8];
  {
    Row24 R = loadrow(in + (imgbase + (size_t)row*512 + col0)*3);
    float cbds[4], crds[4];
    convert_row(R, vY, cbds, crds);
    if ((l & 1) == 0) {                      // even lane = top row of the pair
      const int crow = br*4 + (l >> 1);      // tile chroma row 0..7
      *(float4*)&Cbp[crow][bc*4] = make_float4(cbds[0],cbds[1],cbds[2],cbds[3]);
      *(float4*)&Crp[crow][bc*4] = make_float4(crds[0],crds[1],crds[2],crds[3]);
    }
  }
  __syncthreads();   // tables + chroma planes visible

  // ---------------- luma pipeline (regs + group scratch only)
  jblk8(vY, l, &Scr[g][0], &QTs[0][l][0], &RQs[0][l][0]);

  // ---------------- chroma: 16 blocks on t<128 (groups 0..15 belong to
  // waves 0-1 in both phases — same-wave scratch reuse, no barrier)
  if (t < 128) {
    const int pl = g >> 3;                  // 0 = Cb, 1 = Cr
    float* plane = pl ? &Crp[0][0] : &Cbp[0][0];
    float* rowp  = plane + l*68 + (g & 7)*8;
    float4 L0 = *(const float4*)&rowp[0];
    float4 L1 = *(const float4*)&rowp[4];
    float vC[8] = {L0.x,L0.y,L0.z,L0.w,L1.x,L1.y,L1.z,L1.w};
    jblk8(vC, l, &Scr[g][0], &QTs[1][l][0], &RQs[1][l][0]);  // chroma table!
    *(float4*)&rowp[0] = make_float4(vC[0],vC[1],vC[2],vC[3]);
    *(float4*)&rowp[4] = make_float4(vC[4],vC[5],vC[6],vC[7]);
  }
  __syncthreads();   // chroma rec visible

  // ---------------- output: luma rec in regs; upsample chroma from LDS.
  // /255 after rintf carries no rounding decision -> multiply (R8-proven).
  {
    const int crow = br*4 + (l >> 1);
    float4 CbF = *(const float4*)&Cbp[crow][bc*4];
    float4 CrF = *(const float4*)&Crp[crow][bc*4];
    float cbq[4] = {CbF.x,CbF.y,CbF.z,CbF.w};
    float crq[4] = {CrF.x,CrF.y,CrF.z,CrF.w};
    float ov[24];
    #pragma unroll
    for (int p = 0; p < 8; ++p) {
      float y2  = vY[p] + 128.0f;
      float cb2 = cbq[p>>1] + 128.0f;
      float cr2 = crq[p>>1] + 128.0f;
      float r2 = y2 + 1.402f*(cr2 - 128.0f);
      float g2 = y2 - 0.344136f*(cb2 - 128.0f) - 0.714136f*(cr2 - 128.0f);
      float b2 = y2 + 1.772f*(cb2 - 128.0f);
      ov[3*p+0] = rintf(fminf(fmaxf(r2, 0.0f), 255.0f)) * C255;
      ov[3*p+1] = rintf(fminf(fmaxf(g2, 0.0f), 255.0f)) * C255;
      ov[3*p+2] = rintf(fminf(fmaxf(b2, 0.0f), 255.0f)) * C255;
    }
    float* op = out + (imgbase + (size_t)row*512 + col0)*3;
    ((float4*)op)[0] = make_float4(ov[0], ov[1], ov[2], ov[3]);
    ((float4*)op)[1] = make_float4(ov[4], ov[5], ov[6], ov[7]);
    ((float4*)op)[2] = make_float4(ov[8], ov[9], ov[10],ov[11]);
    ((float4*)op)[3] = make_float4(ov[12],ov[13],ov[14],ov[15]);
    ((float4*)op)[4] = make_float4(ov[16],ov[17],ov[18],ov[19]);
    ((float4*)op)[5] = make_float4(ov[20],ov[21],ov[22],ov[23]);
  }
}

extern "C" void kernel_launch(void* const* d_in, const int* in_sizes, int n_in,
                              void* d_out, int out_size, void* d_ws, size_t ws_size,
                              hipStream_t stream) {
  (void)in_sizes; (void)n_in; (void)d_ws; (void)ws_size; (void)out_size;
  const float* x = (const float*)d_in[0];
  float* out = (float*)d_out;
  dim3 grid(4, 32, 32);   // W/128, H/16, B
  jpeg_rt<<<grid, dim3(256), 0, stream>>>(x, out);
}